// Round 15
// baseline (252.430 us; speedup 1.0000x reference)
//
#include <hip/hip_runtime.h>
#include <hip/hip_fp16.h>

#define NMID 19
#define LOG2E 1.4426950408889634f
#define LN2   0.6931471805599453f

// ---------------------------------------------------------------------------
// Workspace layout (u32 words):
//   [   0..  13] W~1 f32: LOG2E*W1[j][c]           (fc1 in f32 — exact input)
//   [  14..  20] b~1 f32: LOG2E*b1[j]
//   [  21.. 951] Wm rep-h2: l*49+j*7+k -> f16(LOG2E*Wm[l][j][k]) replicated both halves
//   [ 952..1084] bm' rep-h2: l*7+j -> f16(LOG2E*(bm[l][j]-sum_k W)) replicated ("-1" fold)
//   [1085..1098] Wo~ f32: c*7+k -> LOG2E*Wo[c][k]
//   [1099..1100] bo' f32: LOG2E*(bo[c]-sum_k Wo[c][k])
// ---------------------------------------------------------------------------
#define W1_OFF 0
#define B1_OFF 14
#define WM_OFF 21
#define BM_OFF 952
#define WO_OFF 1085
#define BO_OFF 1099
#define NWORDS 1101

typedef _Float16 v2h __attribute__((ext_vector_type(2)));

__device__ __forceinline__ float exp2r(float x) {
#if __has_builtin(__builtin_amdgcn_exp2f)
    return __builtin_amdgcn_exp2f(x);
#else
    return __expf(x * LN2);
#endif
}
__device__ __forceinline__ float log2r(float x) {
#if __has_builtin(__builtin_amdgcn_logf)
    return __builtin_amdgcn_logf(x);
#else
    return __logf(x) * LOG2E;
#endif
}

// packed f16 helpers via native fp16 vectors (lower to v_pk_* VOP3P, full rate)
__device__ __forceinline__ __half2 pmin2(__half2 a, __half2 b) {
    v2h av = __builtin_bit_cast(v2h, a), bv = __builtin_bit_cast(v2h, b);
    return __builtin_bit_cast(__half2, __builtin_elementwise_min(av, bv));
}
__device__ __forceinline__ __half2 pmax2(__half2 a, __half2 b) {
    v2h av = __builtin_bit_cast(v2h, a), bv = __builtin_bit_cast(v2h, b);
    return __builtin_bit_cast(__half2, __builtin_elementwise_max(av, bv));
}
__device__ __forceinline__ __half2 padd2(__half2 a, __half2 b) {
    v2h av = __builtin_bit_cast(v2h, a), bv = __builtin_bit_cast(v2h, b);
    return __builtin_bit_cast(__half2, av + bv);
}
__device__ __forceinline__ __half2 psub2(__half2 a, __half2 b) {
    v2h av = __builtin_bit_cast(v2h, a), bv = __builtin_bit_cast(v2h, b);
    return __builtin_bit_cast(__half2, av - bv);
}

// f32 -> f16 (RTE), replicated into both halves of a u32
__device__ __forceinline__ unsigned int reph(float v) {
    _Float16 h = (_Float16)v;
    unsigned short u = __builtin_bit_cast(unsigned short, h);
    return (unsigned int)u * 0x00010001u;
}

__global__ void prep_kernel(const float* __restrict__ W1, const float* __restrict__ b1,
                            const float* __restrict__ Wm, const float* __restrict__ bm,
                            const float* __restrict__ Wo, const float* __restrict__ bo,
                            unsigned int* __restrict__ ws)
{
    for (int idx = threadIdx.x; idx < NWORDS; idx += blockDim.x) {
        unsigned int uv;
        if (idx < B1_OFF) {                                // W~1 (f32)
            uv = __float_as_uint(LOG2E * W1[idx]);
        } else if (idx < WM_OFF) {                         // b~1 (f32)
            uv = __float_as_uint(LOG2E * b1[idx - B1_OFF]);
        } else if (idx < BM_OFF) {                         // mid weights, replicated f16
            int q = idx - WM_OFF;                          // l*49 + j*7 + k
            uv = reph(LOG2E * Wm[q]);
        } else if (idx < WO_OFF) {                         // mid biases, -1 folded, replicated
            int q = idx - BM_OFF, l = q / 7, j = q % 7;
            const float* W = Wm + l * 49 + j * 7;
            float s = 0.0f;
#pragma unroll
            for (int k = 0; k < 7; ++k) s += W[k];
            uv = reph(LOG2E * (bm[l * 7 + j] - s));
        } else if (idx < BO_OFF) {                         // fc21 weights (f32)
            int q = idx - WO_OFF;                          // c*7 + k
            uv = __float_as_uint(LOG2E * Wo[q]);
        } else {                                           // fc21 biases, -1 folded (f32)
            int c = idx - BO_OFF;
            const float* W = Wo + c * 7;
            float s = 0.0f;
#pragma unroll
            for (int k = 0; k < 7; ++k) s += W[k];
            uv = __float_as_uint(LOG2E * (bo[c] - s));
        }
        ws[idx] = uv;
    }
}

// Packed ELU+1 in log2e domain, ZERO transcendental ops (14 full-rate VALU):
//   P = at*ln2 + 1  (exact branch for at>0; P <= e^a for at<=0)
//   E = 2^atc, atc = clamp(at, -14, 0):
//     magic-add round: m = atc + 1536  (f16 ulp=1 in [1024,2048) -> RTE to int)
//     n = m - 1536 (exact) ; f = atc - n in [-1/2,1/2] (exact)
//     2^f: quartic Taylor, rel err ~6e-5 < f16 half-ulp (4.9e-4)
//     2^n from bits: bits(m) = 0x6000+m = 0x6600+n  (E-field 25, mantissa m-1024)
//       -> (bits(m) - 0x65F1) = n+15 in [1,15]; <<10 = f16 2^n exactly.
//       Packed-safe: low half in [0x65F2,0x6600] so no borrow into high half;
//       (n+15)<<10 <= 0x3C00 stays within each 16-bit half.
//   result = max(P, E): at<=0 -> E=e^a>=P ; at>0 -> E=1<=P. NaN-free.
__device__ __forceinline__ __half2 pelu(__half2 at, __half2 ln22, __half2 one2,
                                        __half2 mag, __half2 nfloor,
                                        __half2 c1, __half2 c2, __half2 c3, __half2 c4) {
    __half2 P   = __hfma2(at, ln22, one2);
    __half2 atc = pmin2(pmax2(at, nfloor), __builtin_bit_cast(__half2, 0u));
    __half2 m   = padd2(atc, mag);          // RTE to integer
    __half2 nf  = psub2(m, mag);            // n as f16, exact
    __half2 f   = psub2(atc, nf);           // in [-0.5, 0.5], exact
    __half2 p   = __hfma2(c4, f, c3);
    p = __hfma2(p, f, c2);
    p = __hfma2(p, f, c1);
    p = __hfma2(p, f, one2);                // 2^f, ~1 ulp f16
    unsigned int mu = __builtin_bit_cast(unsigned int, m);
    unsigned int sb = (mu - 0x65F165F1u) << 10;   // per half: (n+15)<<10 = bits(2^n)
    __half2 S = __builtin_bit_cast(__half2, sb);
    __half2 E = __hmul2(p, S);
    return pmax2(P, E);
}

__global__ __launch_bounds__(256) void net_mlp_kernel(
    const float* __restrict__ x,
    const unsigned int* __restrict__ ws,
    float* __restrict__ out, int B)
{
    int i = blockIdx.x * blockDim.x + threadIdx.x;   // handles rows 4i..4i+3
    if (4 * i >= B) return;

    const float* wsf = reinterpret_cast<const float*>(ws);
    const __half2* wsh = reinterpret_cast<const __half2*>(ws);

    // rows 4i..4i+3: x is [B,2] -> 8 consecutive floats, two float4 loads
    const float4 xA = reinterpret_cast<const float4*>(x)[2 * i + 0]; // rows 0,1
    const float4 xB = reinterpret_cast<const float4*>(x)[2 * i + 1]; // rows 2,3

    const __half2 one2   = __float2half2_rn(1.0f);
    const __half2 ln22   = __float2half2_rn(LN2);
    const __half2 mag    = __float2half2_rn(1536.0f);
    const __half2 nfloor = __float2half2_rn(-14.0f);
    const __half2 c1     = __float2half2_rn(0.69314718f);   // ln2
    const __half2 c2     = __float2half2_rn(0.24022651f);   // ln2^2/2
    const __half2 c3     = __float2half2_rn(0.05550411f);   // ln2^3/6
    const __half2 c4     = __float2half2_rn(0.00961813f);   // ln2^4/24

    // fc1 in f32 (exact input); two independent packed states u (rows 0,1), v (rows 2,3)
    __half2 gu[7], gv[7];
#pragma unroll
    for (int j = 0; j < 7; ++j) {
        float w0 = wsf[W1_OFF + 2 * j], w1 = wsf[W1_OFF + 2 * j + 1], bb = wsf[B1_OFF + j];
        float a0 = fmaf(xA.x, w0, fmaf(xA.y, w1, bb));
        float a1 = fmaf(xA.z, w0, fmaf(xA.w, w1, bb));
        float a2 = fmaf(xB.x, w0, fmaf(xB.y, w1, bb));
        float a3 = fmaf(xB.z, w0, fmaf(xB.w, w1, bb));
        gu[j] = pelu(__floats2half2_rn(a0, a1), ln22, one2, mag, nfloor, c1, c2, c3, c4);
        gv[j] = pelu(__floats2half2_rn(a2, a3), ln22, one2, mag, nfloor, c1, c2, c3, c4);
    }

    // fc2..fc20: 98 v_pk_fma_f16 (4 rows/lane, 2 indep chains) + 14 poly-pelu per layer.
#pragma unroll
    for (int l = 0; l < NMID; ++l) {
        const __half2* wp = wsh + WM_OFF + l * 49;   // wave-uniform -> s_load
        const __half2* bp = wsh + BM_OFF + l * 7;
        __half2 nu[7], nv[7];
#pragma unroll
        for (int j = 0; j < 7; ++j) {
            __half2 au = bp[j];
            __half2 av = bp[j];
#pragma unroll
            for (int k = 0; k < 7; ++k) {
                __half2 w = wp[j * 7 + k];
                au = __hfma2(gu[k], w, au);
                av = __hfma2(gv[k], w, av);
            }
            nu[j] = pelu(au, ln22, one2, mag, nfloor, c1, c2, c3, c4);
            nv[j] = pelu(av, ln22, one2, mag, nfloor, c1, c2, c3, c4);
        }
#pragma unroll
        for (int j = 0; j < 7; ++j) { gu[j] = nu[j]; gv[j] = nv[j]; }
    }

    // fc21 + log_softmax in f32 (carried log2e-scaled)
    float l0[4], l1[4];
#pragma unroll
    for (int r = 0; r < 4; ++r) { l0[r] = wsf[BO_OFF + 0]; l1[r] = wsf[BO_OFF + 1]; }
#pragma unroll
    for (int k = 0; k < 7; ++k) {
        float w0 = wsf[WO_OFF + k], w1 = wsf[WO_OFF + 7 + k];
        float g0 = __low2float(gu[k]), g1 = __high2float(gu[k]);
        float g2 = __low2float(gv[k]), g3 = __high2float(gv[k]);
        l0[0] = fmaf(g0, w0, l0[0]); l1[0] = fmaf(g0, w1, l1[0]);
        l0[1] = fmaf(g1, w0, l0[1]); l1[1] = fmaf(g1, w1, l1[1]);
        l0[2] = fmaf(g2, w0, l0[2]); l1[2] = fmaf(g2, w1, l1[2]);
        l0[3] = fmaf(g3, w0, l0[3]); l1[3] = fmaf(g3, w1, l1[3]);
    }

    float4 oA, oB;
    {
        float m = fmaxf(l0[0], l1[0]), d = fminf(l0[0], l1[0]) - m;
        float zt = m + log2r(1.0f + exp2r(d));
        oA.x = (l0[0] - zt) * LN2; oA.y = (l1[0] - zt) * LN2;
    }
    {
        float m = fmaxf(l0[1], l1[1]), d = fminf(l0[1], l1[1]) - m;
        float zt = m + log2r(1.0f + exp2r(d));
        oA.z = (l0[1] - zt) * LN2; oA.w = (l1[1] - zt) * LN2;
    }
    {
        float m = fmaxf(l0[2], l1[2]), d = fminf(l0[2], l1[2]) - m;
        float zt = m + log2r(1.0f + exp2r(d));
        oB.x = (l0[2] - zt) * LN2; oB.y = (l1[2] - zt) * LN2;
    }
    {
        float m = fmaxf(l0[3], l1[3]), d = fminf(l0[3], l1[3]) - m;
        float zt = m + log2r(1.0f + exp2r(d));
        oB.z = (l0[3] - zt) * LN2; oB.w = (l1[3] - zt) * LN2;
    }
    reinterpret_cast<float4*>(out)[2 * i + 0] = oA;  // rows 4i,4i+1
    reinterpret_cast<float4*>(out)[2 * i + 1] = oB;  // rows 4i+2,4i+3
}

extern "C" void kernel_launch(void* const* d_in, const int* in_sizes, int n_in,
                              void* d_out, int out_size, void* d_ws, size_t ws_size,
                              hipStream_t stream) {
    const float* x  = (const float*)d_in[0];
    const float* W1 = (const float*)d_in[1];
    const float* b1 = (const float*)d_in[2];
    const float* Wm = (const float*)d_in[3];
    const float* bm = (const float*)d_in[4];
    const float* Wo = (const float*)d_in[5];
    const float* bo = (const float*)d_in[6];
    float* out = (float*)d_out;
    unsigned int* ws = (unsigned int*)d_ws;

    prep_kernel<<<1, 256, 0, stream>>>(W1, b1, Wm, bm, Wo, bo, ws);

    const int B = in_sizes[0] / 2;          // x is [B,2]
    const int quads = (B + 3) / 4;          // 4 rows per thread
    const int block = 256;
    const int grid = (quads + block - 1) / block;
    net_mlp_kernel<<<grid, block, 0, stream>>>(x, ws, out, B);
}

// Round 16
// 212.928 us; speedup vs baseline: 1.1855x; 1.1855x over previous
//
#include <hip/hip_runtime.h>
#include <hip/hip_fp16.h>

#define NMID 19
#define LOG2E 1.4426950408889634f
#define LN2   0.6931471805599453f

// ---------------------------------------------------------------------------
// Workspace layout (u32 words):
//   [   0..  13] W~1 f32: LOG2E*W1[j][c]           (fc1 in f32 — exact input)
//   [  14..  20] b~1 f32: LOG2E*b1[j]
//   [  21.. 951] Wm rep-h2: l*49+j*7+k -> f16(LOG2E*Wm[l][j][k]) replicated both halves
//   [ 952..1084] bm' rep-h2: l*7+j -> f16(LOG2E*(bm[l][j]-sum_k W)) replicated ("-1" fold)
//   [1085..1098] Wo~ f32: c*7+k -> LOG2E*Wo[c][k]
//   [1099..1100] bo' f32: LOG2E*(bo[c]-sum_k Wo[c][k])
// ---------------------------------------------------------------------------
#define W1_OFF 0
#define B1_OFF 14
#define WM_OFF 21
#define BM_OFF 952
#define WO_OFF 1085
#define BO_OFF 1099
#define NWORDS 1101

typedef _Float16 v2h __attribute__((ext_vector_type(2)));

__device__ __forceinline__ float exp2r(float x) {
#if __has_builtin(__builtin_amdgcn_exp2f)
    return __builtin_amdgcn_exp2f(x);
#else
    return __expf(x * LN2);
#endif
}
__device__ __forceinline__ float log2r(float x) {
#if __has_builtin(__builtin_amdgcn_logf)
    return __builtin_amdgcn_logf(x);
#else
    return __logf(x) * LOG2E;
#endif
}

// packed f16 min/max via clang elementwise builtins (-> v_pk_min/max_f16)
__device__ __forceinline__ __half2 pmin2(__half2 a, __half2 b) {
    v2h av = __builtin_bit_cast(v2h, a), bv = __builtin_bit_cast(v2h, b);
    return __builtin_bit_cast(__half2, __builtin_elementwise_min(av, bv));
}
__device__ __forceinline__ __half2 pmax2(__half2 a, __half2 b) {
    v2h av = __builtin_bit_cast(v2h, a), bv = __builtin_bit_cast(v2h, b);
    return __builtin_bit_cast(__half2, __builtin_elementwise_max(av, bv));
}

// f32 -> f16 (RTE), replicated into both halves of a u32
__device__ __forceinline__ unsigned int reph(float v) {
    _Float16 h = (_Float16)v;
    unsigned short u = __builtin_bit_cast(unsigned short, h);
    return (unsigned int)u * 0x00010001u;
}

__global__ void prep_kernel(const float* __restrict__ W1, const float* __restrict__ b1,
                            const float* __restrict__ Wm, const float* __restrict__ bm,
                            const float* __restrict__ Wo, const float* __restrict__ bo,
                            unsigned int* __restrict__ ws)
{
    for (int idx = threadIdx.x; idx < NWORDS; idx += blockDim.x) {
        unsigned int uv;
        if (idx < B1_OFF) {                                // W~1 (f32)
            uv = __float_as_uint(LOG2E * W1[idx]);
        } else if (idx < WM_OFF) {                         // b~1 (f32)
            uv = __float_as_uint(LOG2E * b1[idx - B1_OFF]);
        } else if (idx < BM_OFF) {                         // mid weights, replicated f16
            int q = idx - WM_OFF;                          // l*49 + j*7 + k
            uv = reph(LOG2E * Wm[q]);
        } else if (idx < WO_OFF) {                         // mid biases, -1 folded, replicated
            int q = idx - BM_OFF, l = q / 7, j = q % 7;
            const float* W = Wm + l * 49 + j * 7;
            float s = 0.0f;
#pragma unroll
            for (int k = 0; k < 7; ++k) s += W[k];
            uv = reph(LOG2E * (bm[l * 7 + j] - s));
        } else if (idx < BO_OFF) {                         // fc21 weights (f32)
            int q = idx - WO_OFF;                          // c*7 + k
            uv = __float_as_uint(LOG2E * Wo[q]);
        } else {                                           // fc21 biases, -1 folded (f32)
            int c = idx - BO_OFF;
            const float* W = Wo + c * 7;
            float s = 0.0f;
#pragma unroll
            for (int k = 0; k < 7; ++k) s += W[k];
            uv = __float_as_uint(LOG2E * (bo[c] - s));
        }
        ws[idx] = uv;
    }
}

// packed ELU+1 in log2e domain, branchless, 5 ops (2 of them v_exp_f16 ~6cy):
//   E = 2^at ; P = at*ln2 + 1 ; 2^x >= x*ln2+1 for all x (tangent at 0):
//     at<=0: max(P,1)=1, min(E,1)=E           -> e^a      (= elu(a)+1)
//     at> 0: max(P,1)=P, E>=P so min(E,P)=P   -> a+1      (= elu(a)+1)
//   (R15 falsified the poly alternative: hw v_exp_f16 is ~6cy, poly costs more)
__device__ __forceinline__ __half2 pelu(__half2 at, __half2 ln22, __half2 one2) {
    __half2 E = h2exp2(at);
    __half2 P = __hfma2(at, ln22, one2);
    return pmin2(E, pmax2(P, one2));
}

__global__ __launch_bounds__(256) void net_mlp_kernel(
    const float* __restrict__ x,
    const unsigned int* __restrict__ ws,
    float* __restrict__ out, int B)
{
    int i = blockIdx.x * blockDim.x + threadIdx.x;   // handles rows 8i..8i+7
    if (8 * i >= B) return;

    const float* wsf = reinterpret_cast<const float*>(ws);
    const __half2* wsh = reinterpret_cast<const __half2*>(ws);

    // rows 8i..8i+7: x is [B,2] -> 16 consecutive floats, four float4 loads
    const float4 xA = reinterpret_cast<const float4*>(x)[4 * i + 0]; // rows 0,1
    const float4 xB = reinterpret_cast<const float4*>(x)[4 * i + 1]; // rows 2,3
    const float4 xC = reinterpret_cast<const float4*>(x)[4 * i + 2]; // rows 4,5
    const float4 xD = reinterpret_cast<const float4*>(x)[4 * i + 3]; // rows 6,7

    const __half2 one2 = __float2half2_rn(1.0f);
    const __half2 ln22 = __float2half2_rn(LN2);

    // fc1 in f32 (exact input); four independent packed states
    __half2 gu[7], gv[7], gw[7], gz[7];
#pragma unroll
    for (int j = 0; j < 7; ++j) {
        float w0 = wsf[W1_OFF + 2 * j], w1 = wsf[W1_OFF + 2 * j + 1], bb = wsf[B1_OFF + j];
        float a0 = fmaf(xA.x, w0, fmaf(xA.y, w1, bb));
        float a1 = fmaf(xA.z, w0, fmaf(xA.w, w1, bb));
        float a2 = fmaf(xB.x, w0, fmaf(xB.y, w1, bb));
        float a3 = fmaf(xB.z, w0, fmaf(xB.w, w1, bb));
        float a4 = fmaf(xC.x, w0, fmaf(xC.y, w1, bb));
        float a5 = fmaf(xC.z, w0, fmaf(xC.w, w1, bb));
        float a6 = fmaf(xD.x, w0, fmaf(xD.y, w1, bb));
        float a7 = fmaf(xD.z, w0, fmaf(xD.w, w1, bb));
        gu[j] = pelu(__floats2half2_rn(a0, a1), ln22, one2);
        gv[j] = pelu(__floats2half2_rn(a2, a3), ln22, one2);
        gw[j] = pelu(__floats2half2_rn(a4, a5), ln22, one2);
        gz[j] = pelu(__floats2half2_rn(a6, a7), ln22, one2);
    }

    // fc2..fc20: 196 v_pk_fma_f16 (8 rows/lane, 4 indep chains) + 28 pelu per layer.
    // Same SGPR weight words serve all four chains; s_load amortized 4x.
#pragma unroll
    for (int l = 0; l < NMID; ++l) {
        const __half2* wp = wsh + WM_OFF + l * 49;   // wave-uniform -> s_load
        const __half2* bp = wsh + BM_OFF + l * 7;
        __half2 nu[7], nv[7], nw[7], nz[7];
#pragma unroll
        for (int j = 0; j < 7; ++j) {
            __half2 au = bp[j], av = bp[j], aw = bp[j], az = bp[j];
#pragma unroll
            for (int k = 0; k < 7; ++k) {
                __half2 w = wp[j * 7 + k];
                au = __hfma2(gu[k], w, au);
                av = __hfma2(gv[k], w, av);
                aw = __hfma2(gw[k], w, aw);
                az = __hfma2(gz[k], w, az);
            }
            nu[j] = pelu(au, ln22, one2);
            nv[j] = pelu(av, ln22, one2);
            nw[j] = pelu(aw, ln22, one2);
            nz[j] = pelu(az, ln22, one2);
        }
#pragma unroll
        for (int j = 0; j < 7; ++j) { gu[j] = nu[j]; gv[j] = nv[j]; gw[j] = nw[j]; gz[j] = nz[j]; }
    }

    // fc21 + log_softmax in f32 (carried log2e-scaled)
    float l0[8], l1[8];
#pragma unroll
    for (int r = 0; r < 8; ++r) { l0[r] = wsf[BO_OFF + 0]; l1[r] = wsf[BO_OFF + 1]; }
#pragma unroll
    for (int k = 0; k < 7; ++k) {
        float w0 = wsf[WO_OFF + k], w1 = wsf[WO_OFF + 7 + k];
        float g0 = __low2float(gu[k]), g1 = __high2float(gu[k]);
        float g2 = __low2float(gv[k]), g3 = __high2float(gv[k]);
        float g4 = __low2float(gw[k]), g5 = __high2float(gw[k]);
        float g6 = __low2float(gz[k]), g7 = __high2float(gz[k]);
        l0[0] = fmaf(g0, w0, l0[0]); l1[0] = fmaf(g0, w1, l1[0]);
        l0[1] = fmaf(g1, w0, l0[1]); l1[1] = fmaf(g1, w1, l1[1]);
        l0[2] = fmaf(g2, w0, l0[2]); l1[2] = fmaf(g2, w1, l1[2]);
        l0[3] = fmaf(g3, w0, l0[3]); l1[3] = fmaf(g3, w1, l1[3]);
        l0[4] = fmaf(g4, w0, l0[4]); l1[4] = fmaf(g4, w1, l1[4]);
        l0[5] = fmaf(g5, w0, l0[5]); l1[5] = fmaf(g5, w1, l1[5]);
        l0[6] = fmaf(g6, w0, l0[6]); l1[6] = fmaf(g6, w1, l1[6]);
        l0[7] = fmaf(g7, w0, l0[7]); l1[7] = fmaf(g7, w1, l1[7]);
    }

    float4 o[4];
#pragma unroll
    for (int q = 0; q < 4; ++q) {
        {
            float m = fmaxf(l0[2 * q], l1[2 * q]), d = fminf(l0[2 * q], l1[2 * q]) - m;
            float zt = m + log2r(1.0f + exp2r(d));
            o[q].x = (l0[2 * q] - zt) * LN2; o[q].y = (l1[2 * q] - zt) * LN2;
        }
        {
            float m = fmaxf(l0[2 * q + 1], l1[2 * q + 1]), d = fminf(l0[2 * q + 1], l1[2 * q + 1]) - m;
            float zt = m + log2r(1.0f + exp2r(d));
            o[q].z = (l0[2 * q + 1] - zt) * LN2; o[q].w = (l1[2 * q + 1] - zt) * LN2;
        }
        reinterpret_cast<float4*>(out)[4 * i + q] = o[q];
    }
}

extern "C" void kernel_launch(void* const* d_in, const int* in_sizes, int n_in,
                              void* d_out, int out_size, void* d_ws, size_t ws_size,
                              hipStream_t stream) {
    const float* x  = (const float*)d_in[0];
    const float* W1 = (const float*)d_in[1];
    const float* b1 = (const float*)d_in[2];
    const float* Wm = (const float*)d_in[3];
    const float* bm = (const float*)d_in[4];
    const float* Wo = (const float*)d_in[5];
    const float* bo = (const float*)d_in[6];
    float* out = (float*)d_out;
    unsigned int* ws = (unsigned int*)d_ws;

    prep_kernel<<<1, 256, 0, stream>>>(W1, b1, Wm, bm, Wo, bo, ws);

    const int B = in_sizes[0] / 2;          // x is [B,2]
    const int octs = (B + 7) / 8;           // 8 rows per thread
    const int block = 256;
    const int grid = (octs + block - 1) / block;
    net_mlp_kernel<<<grid, block, 0, stream>>>(x, ws, out, B);
}